// Round 7
// baseline (122.248 us; speedup 1.0000x reference)
//
#include <hip/hip_runtime.h>

#define N_NODES 50000
#define E_EDGES 250000
#define IN_F 9
#define OUT_F 84
#define GROUPS 21            // OUT_F / 4
#define BN_EPS 1e-5f

#define NCOPIES 32           // sharded Gram accumulators
#define CAP 32               // slots per destination (P[deg>32] ~ 1e-11, Poisson(5))

#define VDIM 27              // v = (x[9], S0[9], S1[9])
#define NPAIR 378            // VDIM*(VDIM+1)/2 upper-triangle entries of M
#define NM 405               // NPAIR + VDIM (Sigma v)
#define SLEN 408             // padded stride per stat copy
#define NSLOT 196            // paired Gram slots

// K2 tiling: 96 nodes/block, items = (node, quarter q) = 288 over 256 thr
#define NB2 96
#define NT2 ((N_NODES + NB2 - 1) / NB2)              // 521
#define VSTR2 100            // V row stride (96 + 4 pad), 400B, 16B-aligned

// K3 tiling: 96 nodes/block, 21 g-threads x 12 node-lanes x 8 nodes each.
#define FB_TILE 96
#define FB_NT ((N_NODES + FB_TILE - 1) / FB_TILE)    // 521
#define VTS 28               // SX/Vt row: x[9], S0[9], S1[9], pad -> 112B

// K1 grid split: edge blocks + xp-transpose blocks
#define EB ((E_EDGES / 4 + 255) / 256)               // 245
#define XB ((N_NODES + 255) / 256)                   // 196

// ws layout (4-byte units) — cnt and statc contiguous: ONE memset zeroes both
//   [0, 50000)          : cnt[N] (int)
//   [50048, 63104)      : statc 32 x 408 (float)
//   [63232, 3263232)    : slot[N*CAP] int2, rows 256B
//   [3263232, 4663232)  : SX[N*28] combined x/S0/S1 rows (float)
//   [4663232, 4663400)  : ss — scale[84], shift[84]
//   [4663408, 5263408)  : xp[N*12] padded x rows, 48B each, 16B-aligned
#define CNT_OFF   0
#define STATC_OFF 50048
#define ZERO_WORDS 63104     // memset covers cnt + statc
#define SLOT_OFF  63232      // *4 B = 252928, %16 == 0
#define SX_OFF    3263232
#define SS_OFF    4663232
#define XP_OFF    4663408    // *4 B %16 == 0

// ---------------------------------------------------------------------------
// K1: edge blocks bucket edges (4/thread, vector loads); xp blocks build
// padded 12-float x rows so K2 can gather with one dwordx4 per edge-quarter.
// ---------------------------------------------------------------------------
__global__ __launch_bounds__(256)
void fill_slots_kernel(const int* __restrict__ ei,
                       const float* __restrict__ ea,
                       const float* __restrict__ x,
                       int* __restrict__ cnt,
                       int2* __restrict__ slot,
                       float* __restrict__ xp) {
    const int bx = blockIdx.x, tid = threadIdx.x;
    if (bx < EB) {
        int e = (bx * 256 + tid) * 4;
        if (e < E_EDGES) {
            int4   s4 = *(const int4*)&ei[e];
            int4   d4 = *(const int4*)&ei[E_EDGES + e];
            float4 a4 = *(const float4*)&ea[e];
            int pos;
            pos = atomicAdd(&cnt[d4.x], 1);
            if (pos < CAP) slot[d4.x * CAP + pos] = make_int2(s4.x, __float_as_int(a4.x));
            pos = atomicAdd(&cnt[d4.y], 1);
            if (pos < CAP) slot[d4.y * CAP + pos] = make_int2(s4.y, __float_as_int(a4.y));
            pos = atomicAdd(&cnt[d4.z], 1);
            if (pos < CAP) slot[d4.z * CAP + pos] = make_int2(s4.z, __float_as_int(a4.z));
            pos = atomicAdd(&cnt[d4.w], 1);
            if (pos < CAP) slot[d4.w * CAP + pos] = make_int2(s4.w, __float_as_int(a4.w));
        }
    } else {
        int n = (bx - EB) * 256 + tid;
        if (n < N_NODES) {
            const float* xr = x + n * IN_F;
            float4* xd = (float4*)&xp[n * 12];
            xd[0] = make_float4(xr[0], xr[1], xr[2], xr[3]);
            xd[1] = make_float4(xr[4], xr[5], xr[6], xr[7]);
            xd[2] = make_float4(xr[8], 0.f, 0.f, 0.f);
        }
    }
}

// ---------------------------------------------------------------------------
// K2: gather + Gram, 96-node tiles, thread = (node, quarter).
//  - slot records read DIRECTLY from global as int4 pairs (2 records/16B):
//    removes the rec[] LDS stage AND its ~7-way bank conflict (256B rows
//    made nl drop out of the bank index — every inner-loop read conflicted).
//  - x gather: one dwordx4 from xp per edge-quarter (was 9 scalar dwords
//    per edge across the i-threads). VMEM/96 nodes: ~4600 -> ~2600.
//  - accumulation stays register-private per thread (round-5 lesson: LDS
//    float atomics with node-contiguous edges cost 45 us).
// ---------------------------------------------------------------------------
__global__ __launch_bounds__(256)
void gather_gram_kernel(const float* __restrict__ xp,
                        const int*   __restrict__ cnt,
                        const int2*  __restrict__ slot,
                        float* __restrict__ SX,
                        float* __restrict__ statc) {
    __shared__ __align__(16) float V[VDIM * VSTR2];  // [27][100], 10.8 KB
    __shared__ int cnt_s[NB2];
    __shared__ unsigned char sI[NSLOT], sJ[NSLOT];   // paired-slot table

    const int tid = threadIdx.x;
    const int nbase = blockIdx.x * NB2;

    for (int t = tid; t < NSLOT; t += blockDim.x) {
        int tt = t, i = 0;
        while (tt >= ((VDIM - i + 1) >> 1)) { tt -= (VDIM - i + 1) >> 1; ++i; }
        sI[t] = (unsigned char)i;
        sJ[t] = (unsigned char)(i + 2 * tt);
    }
    // zero V pad cols 96..99
    for (int t = tid; t < VDIM * 4; t += blockDim.x)
        V[(t >> 2) * VSTR2 + NB2 + (t & 3)] = 0.f;
    if (tid < NB2) {
        int n = nbase + tid;
        int c = (n < N_NODES) ? cnt[n] : 0;
        cnt_s[tid] = (c > CAP) ? CAP : c;
    }
    __syncthreads();

    // phase 2: 288 (node, quarter) items over 256 threads
    const float4* xp4 = (const float4*)xp;
    for (int it = tid; it < NB2 * 3; it += blockDim.x) {
        int nl = it / 3, q = it - nl * 3;
        int n = nbase + nl;
        float4 xq = make_float4(0.f, 0.f, 0.f, 0.f);
        float4 s0 = xq, s1 = xq;
        if (n < N_NODES) {
            xq = xp4[n * 3 + q];
            int c = cnt_s[nl];
            const int2* r = &slot[n * CAP];
            int k = 0;
            for (; k + 4 <= c; k += 4) {          // 2 dwordx4 recs + 4 dwordx4 x
                int4 p0 = *(const int4*)&r[k];     // (src0,w0,src1,w1)
                int4 p1 = *(const int4*)&r[k + 2]; // (src2,w2,src3,w3)
                float4 a0 = xp4[p0.x * 3 + q];
                float4 a1 = xp4[p0.z * 3 + q];
                float4 a2 = xp4[p1.x * 3 + q];
                float4 a3 = xp4[p1.z * 3 + q];
                float w0 = __int_as_float(p0.y), w1 = __int_as_float(p0.w);
                float w2 = __int_as_float(p1.y), w3 = __int_as_float(p1.w);
                s0.x += (a0.x + a1.x) + (a2.x + a3.x);
                s0.y += (a0.y + a1.y) + (a2.y + a3.y);
                s0.z += (a0.z + a1.z) + (a2.z + a3.z);
                s0.w += (a0.w + a1.w) + (a2.w + a3.w);
                s1.x += w0 * a0.x + w1 * a1.x + w2 * a2.x + w3 * a3.x;
                s1.y += w0 * a0.y + w1 * a1.y + w2 * a2.y + w3 * a3.y;
                s1.z += w0 * a0.z + w1 * a1.z + w2 * a2.z + w3 * a3.z;
                s1.w += w0 * a0.w + w1 * a1.w + w2 * a2.w + w3 * a3.w;
            }
            for (; k < c; ++k) {
                int2 r0 = r[k];
                float4 a0 = xp4[r0.x * 3 + q];
                float w0 = __int_as_float(r0.y);
                s0.x += a0.x; s0.y += a0.y; s0.z += a0.z; s0.w += a0.w;
                s1.x += w0 * a0.x; s1.y += w0 * a0.y;
                s1.z += w0 * a0.z; s1.w += w0 * a0.w;
            }
            // SX row writes (features f = 4q+j, valid f < 9)
            float* sx = SX + n * VTS;
            int f0 = q * 4;
            sx[f0]      = xq.x;
            sx[9 + f0]  = s0.x;
            sx[18 + f0] = s1.x;
            if (q < 2) {
                sx[f0 + 1] = xq.y; sx[9 + f0 + 1] = s0.y; sx[18 + f0 + 1] = s1.y;
                sx[f0 + 2] = xq.z; sx[9 + f0 + 2] = s0.z; sx[18 + f0 + 2] = s1.z;
                sx[f0 + 3] = xq.w; sx[9 + f0 + 3] = s0.w; sx[18 + f0 + 3] = s1.w;
            }
        }
        // V writes (zeros for invalid nodes keep the Gram exact)
        int f0 = q * 4;
        V[f0 * VSTR2 + nl]        = xq.x;
        V[(9 + f0) * VSTR2 + nl]  = s0.x;
        V[(18 + f0) * VSTR2 + nl] = s1.x;
        if (q < 2) {
            V[(f0 + 1) * VSTR2 + nl]      = xq.y;
            V[(9 + f0 + 1) * VSTR2 + nl]  = s0.y;
            V[(18 + f0 + 1) * VSTR2 + nl] = s1.y;
            V[(f0 + 2) * VSTR2 + nl]      = xq.z;
            V[(9 + f0 + 2) * VSTR2 + nl]  = s0.z;
            V[(18 + f0 + 2) * VSTR2 + nl] = s1.z;
            V[(f0 + 3) * VSTR2 + nl]      = xq.w;
            V[(9 + f0 + 3) * VSTR2 + nl]  = s0.w;
            V[(18 + f0 + 3) * VSTR2 + nl] = s1.w;
        }
    }
    __syncthreads();

    // phase 3: Gram — 196 paired slots + 27 sums, float4 over 25 chunks
    float* sc = statc + (blockIdx.x & (NCOPIES - 1)) * SLEN;
    for (int t = tid; t < NSLOT + VDIM; t += blockDim.x) {
        if (t < NSLOT) {
            int i = sI[t], j0 = sJ[t];
            int h2 = (j0 < VDIM - 1);
            const float4* vi = (const float4*)&V[i * VSTR2];
            const float4* va = (const float4*)&V[j0 * VSTR2];
            const float4* vb = (const float4*)&V[(j0 + h2) * VSTR2];
            float acc0 = 0.f, acc1 = 0.f;
#pragma unroll
            for (int m = 0; m < VSTR2 / 4; ++m) {
                float4 a = vi[m], p = va[m], q4 = vb[m];
                acc0 += a.x * p.x + a.y * p.y + a.z * p.z + a.w * p.w;
                acc1 += a.x * q4.x + a.y * q4.y + a.z * q4.z + a.w * q4.w;
            }
            int base = i * VDIM - (i * (i - 1)) / 2;
            atomicAdd(&sc[base + (j0 - i)], acc0);
            if (h2) atomicAdd(&sc[base + (j0 - i) + 1], acc1);
        } else {
            int r = t - NSLOT;
            const float4* vi = (const float4*)&V[r * VSTR2];
            float acc = 0.f;
#pragma unroll
            for (int m = 0; m < VSTR2 / 4; ++m) {
                float4 a = vi[m];
                acc += (a.x + a.y) + (a.z + a.w);
            }
            atomicAdd(&sc[NPAIR + r], acc);
        }
    }
}

// ---------------------------------------------------------------------------
// K2b: reduce Gram copies, derive BN scale/shift ONCE. 1 block. (unchanged)
// ---------------------------------------------------------------------------
__global__ __launch_bounds__(256)
void scale_kernel(const float* __restrict__ nw,
                  const float* __restrict__ nb,
                  const float* __restrict__ root,
                  const float* __restrict__ bias,
                  const float* __restrict__ gamma,
                  const float* __restrict__ beta,
                  const float* __restrict__ statc,
                  float* __restrict__ ss) {
    __shared__ float M[NM];
    const int tid = threadIdx.x;
    for (int t = tid; t < NM; t += blockDim.x) {
        float a = 0.f;
#pragma unroll
        for (int c = 0; c < NCOPIES; ++c) a += statc[c * SLEN + t];
        M[t] = a;
    }
    __syncthreads();
    if (tid < OUT_F) {
        const int o = tid;
        float c[VDIM];
#pragma unroll
        for (int i = 0; i < IN_F; ++i) {
            c[i]      = root[i * OUT_F + o];
            c[9 + i]  = nb[i * OUT_F + o];     // S0 * B
            c[18 + i] = nw[i * OUT_F + o];     // S1 * W
        }
        float sv = 0.f;
#pragma unroll
        for (int i = 0; i < VDIM; ++i) sv += M[NPAIR + i] * c[i];
        float q = 0.f;
        int t2 = 0;
        for (int i = 0; i < VDIM; ++i) {
            q += c[i] * c[i] * M[t2++];
            for (int j = i + 1; j < VDIM; ++j)
                q += 2.f * c[i] * c[j] * M[t2++];
        }
        const float b = bias[o];
        const float inv_n = 1.0f / (float)N_NODES;
        float mean  = (sv + (float)N_NODES * b) * inv_n;
        float sumsq = q + 2.f * b * sv + (float)N_NODES * b * b;
        float var   = sumsq * inv_n - mean * mean;
        float scl   = rsqrtf(var + BN_EPS) * gamma[o];
        ss[o]         = scl;
        ss[OUT_F + o] = beta[o] - mean * scl;
    }
}

// ---------------------------------------------------------------------------
// K3: matvec + normalized write (round-6 form, measured good). Weights in
// registers (float4 C[27], static indexing), __launch_bounds__(256,2);
// SX rows already in Vt layout -> staging is one coalesced float4 copy.
// ---------------------------------------------------------------------------
__global__ __launch_bounds__(256, 2)
void final_kernel(const float* __restrict__ SX,
                  const float* __restrict__ nw,
                  const float* __restrict__ nb,
                  const float* __restrict__ root,
                  const float* __restrict__ bias,
                  const float* __restrict__ ss,
                  float* __restrict__ out) {
    __shared__ __align__(16) float4 Ws[IN_F * GROUPS];
    __shared__ __align__(16) float4 Bs[IN_F * GROUPS];
    __shared__ __align__(16) float4 Rs[IN_F * GROUPS];
    __shared__ __align__(16) float Vt[FB_TILE * VTS];   // 10.5 KB

    const int tid = threadIdx.x;
    const int nbase = blockIdx.x * FB_TILE;
    const int nn = (N_NODES - nbase < FB_TILE) ? (N_NODES - nbase) : FB_TILE;

    for (int t = tid; t < IN_F * GROUPS; t += blockDim.x) {
        Ws[t] = ((const float4*)nw)[t];
        Bs[t] = ((const float4*)nb)[t];
        Rs[t] = ((const float4*)root)[t];
    }

    {
        const float4* sx4 = (const float4*)(SX + nbase * VTS);
        float4* vt4 = (float4*)Vt;
        const int nf4 = (nn * VTS) >> 2;
        for (int f = tid; f < nf4; f += blockDim.x)
            vt4[f] = sx4[f];
    }
    __syncthreads();

    const int g = tid % GROUPS;
    const int lane = tid / GROUPS;
    if (tid < 252) {
        float4 C[27];
#pragma unroll
        for (int i = 0; i < IN_F; ++i) {
            C[i]      = Rs[i * GROUPS + g];   // pairs with x
            C[9 + i]  = Bs[i * GROUPS + g];   // pairs with S0
            C[18 + i] = Ws[i * GROUPS + g];   // pairs with S1
        }
        const float4 b4  = ((const float4*)bias)[g];
        const float4 sc4 = ((const float4*)ss)[g];
        const float4 sh4 = ((const float4*)(ss + OUT_F))[g];
#pragma unroll
        for (int k = 0; k < 8; ++k) {
            const int nl = k * 12 + lane;
            const int n  = nbase + nl;
            if (n < N_NODES) {
                const float* vr = &Vt[nl * VTS];
                float4 a0 = *(const float4*)(vr + 0);
                float4 a1 = *(const float4*)(vr + 4);
                float4 a2 = *(const float4*)(vr + 8);
                float4 a3 = *(const float4*)(vr + 12);
                float4 a4 = *(const float4*)(vr + 16);
                float4 a5 = *(const float4*)(vr + 20);
                float4 a6 = *(const float4*)(vr + 24);
                float4 acc = b4;
#define ACC(VC, IDX)                                                      \
                acc.x += (VC) * C[IDX].x;                                 \
                acc.y += (VC) * C[IDX].y;                                 \
                acc.z += (VC) * C[IDX].z;                                 \
                acc.w += (VC) * C[IDX].w;
                ACC(a0.x, 0)  ACC(a0.y, 1)  ACC(a0.z, 2)  ACC(a0.w, 3)
                ACC(a1.x, 4)  ACC(a1.y, 5)  ACC(a1.z, 6)  ACC(a1.w, 7)
                ACC(a2.x, 8)  ACC(a2.y, 9)  ACC(a2.z, 10) ACC(a2.w, 11)
                ACC(a3.x, 12) ACC(a3.y, 13) ACC(a3.z, 14) ACC(a3.w, 15)
                ACC(a4.x, 16) ACC(a4.y, 17) ACC(a4.z, 18) ACC(a4.w, 19)
                ACC(a5.x, 20) ACC(a5.y, 21) ACC(a5.z, 22) ACC(a5.w, 23)
                ACC(a6.x, 24) ACC(a6.y, 25) ACC(a6.z, 26)
#undef ACC
                acc.x = acc.x * sc4.x + sh4.x;
                acc.y = acc.y * sc4.y + sh4.y;
                acc.z = acc.z * sc4.z + sh4.z;
                acc.w = acc.w * sc4.w + sh4.w;
                *(float4*)&out[n * OUT_F + g * 4] = acc;
            }
        }
    }
}

extern "C" void kernel_launch(void* const* d_in, const int* in_sizes, int n_in,
                              void* d_out, int out_size, void* d_ws, size_t ws_size,
                              hipStream_t stream) {
    const float* x     = (const float*)d_in[0];
    const int*   ei    = (const int*)d_in[1];     // int64 in ref -> int32 here
    const float* ea    = (const float*)d_in[2];
    const float* nw    = (const float*)d_in[3];
    const float* nb    = (const float*)d_in[4];
    const float* root  = (const float*)d_in[5];
    const float* bias  = (const float*)d_in[6];
    const float* gamma = (const float*)d_in[7];
    const float* beta  = (const float*)d_in[8];
    float*       out   = (float*)d_out;

    float* wsf   = (float*)d_ws;
    int*   wsi   = (int*)d_ws;
    int*   cnt   = wsi + CNT_OFF;            // N ints
    float* statc = wsf + STATC_OFF;          // 32 x 408 floats
    int2*  slot  = (int2*)(wsi + SLOT_OFF);  // N*CAP int2 (12.8 MB)
    float* SX    = wsf + SX_OFF;             // N*28 floats (5.6 MB)
    float* ss    = wsf + SS_OFF;             // scale[84] + shift[84]
    float* xp    = wsf + XP_OFF;             // N*12 padded x rows

    // one memset zeroes cnt AND statc (contiguous; 0.0f == all-zero bits)
    hipMemsetAsync(wsi, 0, ZERO_WORDS * sizeof(int), stream);
    fill_slots_kernel<<<EB + XB, 256, 0, stream>>>(ei, ea, x, cnt, slot, xp);
    gather_gram_kernel<<<NT2, 256, 0, stream>>>(xp, cnt, slot, SX, statc);
    scale_kernel<<<1, 256, 0, stream>>>(nw, nb, root, bias, gamma, beta, statc, ss);
    final_kernel<<<FB_NT, 256, 0, stream>>>(SX, nw, nb, root, bias, ss, out);
}